// Round 7
// baseline (727.973 us; speedup 1.0000x reference)
//
#include <hip/hip_runtime.h>
#include <hip/hip_bf16.h>

#define B_    4
#define T_    1024
#define E_    1024
#define H_    16
#define DH_   64
#define KV_   2817
#define KVP_  2880
#define MEML_ 1793
#define POSP_ 3200
#define SC2_  0.18033688011112042f   /* (1/8) * log2(e) */

typedef __attribute__((ext_vector_type(4))) float f32x4;
typedef __attribute__((ext_vector_type(8))) short bf8;
typedef __attribute__((ext_vector_type(4))) unsigned short u16x4;
typedef __attribute__((ext_vector_type(8))) unsigned short u16x8;
typedef unsigned short u16;

static __device__ __forceinline__ u16 f2b(float f) {
  union { __hip_bfloat16 b; u16 s; } u;
  u.b = __float2bfloat16(f);
  return u.s;
}

static __device__ __forceinline__ void gl_lds16(const void* g, void* l) {
  __builtin_amdgcn_global_load_lds(
      (const __attribute__((address_space(1))) unsigned int*)g,
      (__attribute__((address_space(3))) unsigned int*)l, 16, 0, 0);
}

static __device__ __forceinline__ f32x4 mfma16(bf8 a, bf8 b, f32x4 c) {
  return __builtin_amdgcn_mfma_f32_16x16x32_bf16(a, b, c, 0, 0, 0);
}

// ---------------------------------------------------------------- prep kernels

__global__ void k_build_kvin(const float* __restrict__ x, const float* __restrict__ mem,
                             const float* __restrict__ cm0, const float* __restrict__ cm1,
                             const float* __restrict__ ltm, u16* __restrict__ kvin)
{
  int idx = blockIdx.x * 256 + threadIdx.x;          // one float4 per thread
  if (idx >= B_ * KV_ * 256) return;
  int e4 = idx & 255;
  int jt = idx >> 8;                                  // b*2817 + j
  int b = jt / KV_;
  int j = jt - b * KV_;
  const float* src;
  if (j < 1)          src = ltm + (long)b * E_;
  else if (j < 513)   src = cm0 + ((long)b * 512 + (j - 1)) * E_;
  else if (j < 769)   src = cm1 + ((long)b * 256 + (j - 513)) * E_;
  else if (j < 1793)  src = mem + ((long)b * 1024 + (j - 769)) * E_;
  else                src = x   + ((long)b * 1024 + (j - 1793)) * E_;
  float4 v = ((const float4*)src)[e4];
  u16x4 o; o[0] = f2b(v.x); o[1] = f2b(v.y); o[2] = f2b(v.z); o[3] = f2b(v.w);
  *(u16x4*)(kvin + (long)jt * E_ + e4 * 4) = o;
}

__global__ void k_f2b4(const float* __restrict__ s, u16* __restrict__ d, int n4)
{
  int i = blockIdx.x * 256 + threadIdx.x;
  if (i >= n4) return;
  float4 v = ((const float4*)s)[i];
  u16x4 o; o[0] = f2b(v.x); o[1] = f2b(v.y); o[2] = f2b(v.z); o[3] = f2b(v.w);
  *(u16x4*)(d + (long)i * 4) = o;
}

__global__ void k_posb(const float* __restrict__ pos, u16* __restrict__ pb)
{
  int idx = blockIdx.x * 256 + threadIdx.x;          // one float4 per thread
  if (idx >= H_ * POSP_ * 16) return;
  int e4 = idx & 15;
  int rest = idx >> 4;
  int m = rest % POSP_;
  int h = rest / POSP_;
  u16x4 o;
  if (m < KV_) {
    float4 v = ((const float4*)(pos + ((long)h * KV_ + m) * DH_))[e4];
    o[0] = f2b(v.x); o[1] = f2b(v.y); o[2] = f2b(v.z); o[3] = f2b(v.w);
  } else {
    o[0] = 0; o[1] = 0; o[2] = 0; o[3] = 0;
  }
  *(u16x4*)(pb + ((long)h * POSP_ + m) * DH_ + e4 * 4) = o;
}

// zero pad rows j in [2817, 2880) of K and V, both [b,h,j,d] layout
__global__ void k_zeropad(u16* __restrict__ kb, u16* __restrict__ vb)
{
  int idx = blockIdx.x * 256 + threadIdx.x;
  const int NK = 64 * 63 * 64;      // (b*h) * padrows * d
  if (idx < NK) {
    int bh = idx / (63 * 64);
    int r  = idx - bh * (63 * 64);
    int j  = 2817 + (r >> 6);
    int d  = r & 63;
    kb[((long)bh * KVP_ + j) * DH_ + d] = 0;
  } else if (idx < 2 * NK) {
    int i2 = idx - NK;
    int bh = i2 / (63 * 64);
    int r  = i2 - bh * (63 * 64);
    int j  = 2817 + (r >> 6);
    int d  = r & 63;
    vb[((long)bh * KVP_ + j) * DH_ + d] = 0;
  }
}

// transpose V: vb [bh][j 2880][d 64] -> vtb [bh][d 64][j 2880], 64x64 LDS tiles
__global__ __launch_bounds__(256)
void k_vtrans(const u16* __restrict__ vb, u16* __restrict__ vtb)
{
  __shared__ u16 tile[64][66];
  const int bh = blockIdx.y;
  const int j0 = blockIdx.x * 64;
  const u16* src = vb + ((long)bh * KVP_ + j0) * DH_;
  u16* dst = vtb + (long)bh * DH_ * KVP_ + j0;
  const int t = threadIdx.x;
#pragma unroll
  for (int c = 0; c < 2; ++c) {
    int lin = c * 256 + t;
    int r = lin >> 3, ch = (lin & 7) * 8;
    u16x8 v = *(const u16x8*)(src + (long)r * DH_ + ch);
    *(u16x4*)&tile[r][ch]     = *(const u16x4*)&v;
    *(u16x4*)&tile[r][ch + 4] = *(((const u16x4*)&v) + 1);
  }
  __syncthreads();
#pragma unroll
  for (int c = 0; c < 2; ++c) {
    int lin = c * 256 + t;
    int d = lin >> 3, jc = (lin & 7) * 8;
    u16x8 o;
#pragma unroll
    for (int e = 0; e < 8; ++e) o[e] = tile[jc + e][d];
    *(u16x8*)(dst + (long)d * KVP_ + jc) = o;
  }
}

// ---------------------------------------------------------------- GEMM (A[M,K] bf16 row-major, B[N,K] bf16 row-major -> C = A.B^T)
// Accumulators are 16 NAMED f32x4 registers (no arrays -> no scratch, rule #20).

template<int MODE>
__global__ __launch_bounds__(256)
void gemm_bt(const u16* __restrict__ A, const u16* __restrict__ Bw,
             u16* __restrict__ Out16, u16* __restrict__ Out16b,
             float* __restrict__ Outf, const float* __restrict__ bias)
{
  constexpr int Kd = 1024;
  constexpr int NT = (MODE == 1) ? 16 : 8;
  __shared__ u16 As[128 * 32];
  __shared__ u16 Bs[128 * 32];
  const int bid = blockIdx.x;
  const int mt = bid / NT, ntl = bid - mt * NT;
  const int m0 = mt * 128, n0 = ntl * 128;
  const int t = threadIdx.x;
  const int w = t >> 6, lane = t & 63;
  const int wr = w >> 1, wc = w & 1;
  const int l15 = lane & 15, lg = lane >> 4;
  const int xr = l15 & 3;                    // row&3 for fragment rows
  const int xo = (lg ^ xr) << 4;             // XOR-swizzled chunk byte offset

  f32x4 c00{}, c01{}, c02{}, c03{}, c10{}, c11{}, c12{}, c13{},
        c20{}, c21{}, c22{}, c23{}, c30{}, c31{}, c32{}, c33{};

  long growA[2]; int nrowB[2], xcA[2];
#pragma unroll
  for (int c = 0; c < 2; ++c) {
    int lin = c * 256 + t;
    int row = lin >> 2;
    xcA[c] = ((lin & 3) ^ (row & 3)) * 8;    // XOR-swizzled k-chunk (source side)
    int m = m0 + row;
    long grow;
    if (MODE == 0)      { int b = m >> 10; grow = (long)b * KV_ + MEML_ + (m & 1023); }
    else if (MODE == 1) { grow = (m > 11267) ? 11267 : m; }
    else                { grow = m; }
    growA[c] = grow;
    nrowB[c] = n0 + row;
  }

  const char* pa = (const char*)As + (wr * 64 + l15) * 64 + xo;
  const char* pb = (const char*)Bs + (wc * 64 + l15) * 64 + xo;

  for (int kt = 0; kt < Kd; kt += 32) {
#pragma unroll
    for (int c = 0; c < 2; ++c) {
      int lin = c * 256 + t;
      gl_lds16(A + growA[c] * Kd + kt + xcA[c], (char*)As + lin * 16);
      gl_lds16(Bw + (long)nrowB[c] * Kd + kt + xcA[c], (char*)Bs + lin * 16);
    }
    __syncthreads();
    bf8 a0 = *(const bf8*)(pa);
    bf8 a1 = *(const bf8*)(pa + 16 * 64);
    bf8 a2 = *(const bf8*)(pa + 32 * 64);
    bf8 a3 = *(const bf8*)(pa + 48 * 64);
    bf8 b0 = *(const bf8*)(pb);
    bf8 b1 = *(const bf8*)(pb + 16 * 64);
    bf8 b2 = *(const bf8*)(pb + 32 * 64);
    bf8 b3 = *(const bf8*)(pb + 48 * 64);
    c00 = mfma16(a0, b0, c00); c01 = mfma16(a0, b1, c01);
    c02 = mfma16(a0, b2, c02); c03 = mfma16(a0, b3, c03);
    c10 = mfma16(a1, b0, c10); c11 = mfma16(a1, b1, c11);
    c12 = mfma16(a1, b2, c12); c13 = mfma16(a1, b3, c13);
    c20 = mfma16(a2, b0, c20); c21 = mfma16(a2, b1, c21);
    c22 = mfma16(a2, b2, c22); c23 = mfma16(a2, b3, c23);
    c30 = mfma16(a3, b0, c30); c31 = mfma16(a3, b1, c31);
    c32 = mfma16(a3, b2, c32); c33 = mfma16(a3, b3, c33);
    __syncthreads();
  }

  auto epi = [&](int mi, int ni, f32x4 ac) {
    int mb = m0 + wr * 64 + mi * 16 + lg * 4;
    int n  = n0 + wc * 64 + ni * 16 + l15;
    if (MODE == 0) {
      int hh = n >> 6, d = n & 63;
#pragma unroll
      for (int g = 0; g < 4; ++g) {
        int m = mb + g; int b = m >> 10, tq = m & 1023;
        Out16[((long)(b * 16 + hh) * T_ + tq) * DH_ + d] = f2b(ac[g]);
      }
    } else if (MODE == 1) {
      if (n < 1024) {
        int hh = n >> 6, d = n & 63;
#pragma unroll
        for (int g = 0; g < 4; ++g) {
          int m = mb + g; if (m >= 11268) continue;
          int b = m / KV_, j = m - b * KV_;
          Out16[((long)(b * 16 + hh) * KVP_ + j) * DH_ + d] = f2b(ac[g]);
        }
      } else {
        int n2 = n - 1024, hh = n2 >> 6, d = n2 & 63;
#pragma unroll
        for (int g = 0; g < 4; ++g) {
          int m = mb + g; if (m >= 11268) continue;
          int b = m / KV_, j = m - b * KV_;
          Out16b[((long)(b * 16 + hh) * KVP_ + j) * DH_ + d] = f2b(ac[g]);
        }
      }
    } else {
      float bv = bias[n];
#pragma unroll
      for (int g = 0; g < 4; ++g) {
        int m = mb + g;
        Outf[(long)m * E_ + n] = ac[g] + bv;
      }
    }
  };

  epi(0, 0, c00); epi(0, 1, c01); epi(0, 2, c02); epi(0, 3, c03);
  epi(1, 0, c10); epi(1, 1, c11); epi(1, 2, c12); epi(1, 3, c13);
  epi(2, 0, c20); epi(2, 1, c21); epi(2, 2, c22); epi(2, 3, c23);
  epi(3, 0, c30); epi(3, 1, c31); epi(3, 2, c32); epi(3, 3, c33);
}

// ---------------------------------------------------------------- attention
// grid (8, 64): x = 128-row query tile (reversed order), y = b*16+h.
// 8 waves x 16 query rows, 512 threads. Double-buffered K/V LDS shared by
// all 8 waves, 2-phase pipeline with counted vmcnt, pos via direct global
// B-fragment loads software-pipelined one tile ahead.

__global__ __launch_bounds__(512, 4)
void attn_kernel(const u16* __restrict__ Qb, const u16* __restrict__ Kb,
                 const u16* __restrict__ Vtb, const u16* __restrict__ Pb,
                 u16* __restrict__ Ob)
{
  __shared__ u16 Ks[2][64 * 64];    // [n][d], XOR-swizzled rows
  __shared__ u16 Vs[2][64 * 64];    // [d][n], XOR-swizzled rows
  __shared__ float Pg[8][16 * 84];  // per-wave scratch (pos gather, then P)

  const int i0 = (7 - blockIdx.x) * 128;   // reversed: longest blocks first
  const int bh = blockIdx.y;
  const int h  = bh & 15;
  const int t  = threadIdx.x;
  const int w  = t >> 6, lane = t & 63;
  const int l15 = lane & 15, lg = lane >> 4, lk8 = lg * 8;
  const int iwb = i0 + w * 16;

  const u16* Qp = Qb + ((long)bh * T_ + i0) * DH_;
  const u16* Kp = Kb + (long)bh * KVP_ * DH_;
  const u16* Vp = Vtb + (long)bh * DH_ * KVP_;
  const u16* Pp = Pb + (long)h * POSP_ * DH_;
  float* Pgw = &Pg[w][0];

  bf8 qf0 = *(const bf8*)(Qp + (w * 16 + l15) * DH_ + lk8);
  bf8 qf1 = *(const bf8*)(Qp + (w * 16 + l15) * DH_ + 32 + lk8);

  f32x4 Oa[4] = {};
  float Mr[4] = {-1e30f, -1e30f, -1e30f, -1e30f};
  float Lr[4] = {0.f, 0.f, 0.f, 0.f};

  const int ntiles = 31 + (i0 >> 6);

  // stage K,V tile tl into buffer bsel (2 gl_lds16 per thread, 512 threads)
  const int srow = t >> 3;
  const int ssc  = ((t & 7) ^ (srow & 7)) * 8;
  auto STAGE = [&](int tl, int bsel) {
    const int n0s = tl * 64;
    gl_lds16(Kp + (long)(n0s + srow) * DH_ + ssc, (char*)&Ks[bsel][0] + t * 16);
    gl_lds16(Vp + (long)srow * KVP_ + n0s + ssc, (char*)&Vs[bsel][0] + t * 16);
  };

  // pos band B-fragments for tile tl (10 named regs, 16B loads)
  bf8 p00, p01, p10, p11, p20, p21, p30, p31, p40, p41;
  auto POSLOAD = [&](int tl) {
    const u16* pp = Pp + (long)(tl * 64 - i0 + 1008 - 16 * w + l15) * DH_ + lk8;
    p00 = *(const bf8*)(pp);             p01 = *(const bf8*)(pp + 32);
    p10 = *(const bf8*)(pp + 16 * DH_);  p11 = *(const bf8*)(pp + 16 * DH_ + 32);
    p20 = *(const bf8*)(pp + 32 * DH_);  p21 = *(const bf8*)(pp + 32 * DH_ + 32);
    p30 = *(const bf8*)(pp + 48 * DH_);  p31 = *(const bf8*)(pp + 48 * DH_ + 32);
    p40 = *(const bf8*)(pp + 64 * DH_);  p41 = *(const bf8*)(pp + 64 * DH_ + 32);
  };

  // prologue: stage tile 0, preload pos tile 0, drain stages only
  STAGE(0, 0);
  __builtin_amdgcn_sched_barrier(0);
  POSLOAD(0);
  asm volatile("s_waitcnt vmcnt(10)" ::: "memory");
  __builtin_amdgcn_s_barrier();

  for (int tl = 0; tl < ntiles; ++tl) {
    const int bsel = tl & 1;
    const int n0 = tl * 64;
    const bool more = (tl + 1 < ntiles);
    if (more) STAGE(tl + 1, bsel ^ 1);
    __builtin_amdgcn_sched_barrier(0);

    const char* Kbase = (const char*)&Ks[bsel][0];
    const char* Vbase = (const char*)&Vs[bsel][0];

    // QK^T : 4 column fragments of 16 keys
    f32x4 sf[4];
#pragma unroll
    for (int cf = 0; cf < 4; ++cf) {
      int row = cf * 16 + l15;
      int x0 = (lk8 * 2) ^ ((row & 7) << 4);
      int x1 = (64 + lk8 * 2) ^ ((row & 7) << 4);
      f32x4 z = {0.f, 0.f, 0.f, 0.f};
      z = mfma16(qf0, *(const bf8*)(Kbase + (row << 7) + x0), z);
      z = mfma16(qf1, *(const bf8*)(Kbase + (row << 7) + x1), z);
      sf[cf] = z;
    }

    // pos band MFMAs from registers; scatter to per-wave scratch (stride 84)
    {
      f32x4 z0 = {0.f,0.f,0.f,0.f}, z1 = {0.f,0.f,0.f,0.f}, z2 = {0.f,0.f,0.f,0.f},
            z3 = {0.f,0.f,0.f,0.f}, z4 = {0.f,0.f,0.f,0.f};
      z0 = mfma16(qf0, p00, z0); z0 = mfma16(qf1, p01, z0);
      z1 = mfma16(qf0, p10, z1); z1 = mfma16(qf1, p11, z1);
      z2 = mfma16(qf0, p20, z2); z2 = mfma16(qf1, p21, z2);
      z3 = mfma16(qf0, p30, z3); z3 = mfma16(qf1, p31, z3);
      z4 = mfma16(qf0, p40, z4); z4 = mfma16(qf1, p41, z4);
#pragma unroll
      for (int g = 0; g < 4; ++g) {
        int rb = (lg * 4 + g) * 84 + l15;
        Pgw[rb]      = z0[g];
        Pgw[rb + 16] = z1[g];
        Pgw[rb + 32] = z2[g];
        Pgw[rb + 48] = z3[g];
        Pgw[rb + 64] = z4[g];
      }
    }
    if (more) POSLOAD(tl + 1);

    // diagonal gather + scale + mask
    float sv[4][4];
    const bool mm = (n0 + 63) > (MEML_ + iwb);
#pragma unroll
    for (int cf = 0; cf < 4; ++cf) {
      int c = cf * 16 + l15;
#pragma unroll
      for (int g = 0; g < 4; ++g) {
        int r = lg * 4 + g;
        float pv = Pgw[r * 84 + (c + 15 - r)];
        float s2 = (sf[cf][g] + pv) * SC2_;
        if (mm && (n0 + c) > (MEML_ + iwb + r)) s2 = -1e30f;
        sv[cf][g] = s2;
      }
    }
    // online softmax (exp2 domain), per query row
#pragma unroll
    for (int g = 0; g < 4; ++g) {
      float v = fmaxf(fmaxf(sv[0][g], sv[1][g]), fmaxf(sv[2][g], sv[3][g]));
      v = fmaxf(v, __shfl_xor(v, 1)); v = fmaxf(v, __shfl_xor(v, 2));
      v = fmaxf(v, __shfl_xor(v, 4)); v = fmaxf(v, __shfl_xor(v, 8));
      float Mn = fmaxf(Mr[g], v);
      float corr = exp2f(Mr[g] - Mn);
      Mr[g] = Mn;
      float p0 = exp2f(sv[0][g] - Mn), p1 = exp2f(sv[1][g] - Mn);
      float p2 = exp2f(sv[2][g] - Mn), p3 = exp2f(sv[3][g] - Mn);
      float ls = p0 + p1 + p2 + p3;
      ls += __shfl_xor(ls, 1); ls += __shfl_xor(ls, 2);
      ls += __shfl_xor(ls, 4); ls += __shfl_xor(ls, 8);
      Lr[g] = Lr[g] * corr + ls;
#pragma unroll
      for (int of = 0; of < 4; ++of) Oa[of][g] *= corr;
      int r = lg * 4 + g;
      Pgw[r * 84 + l15]      = p0;
      Pgw[r * 84 + 16 + l15] = p1;
      Pgw[r * 84 + 32 + l15] = p2;
      Pgw[r * 84 + 48 + l15] = p3;
    }
    // PV: read P back as A-fragments (f32 -> bf16), V from transposed LDS tile
#pragma unroll
    for (int ks = 0; ks < 2; ++ks) {
      f32x4 a0 = *(const f32x4*)&Pgw[l15 * 84 + ks * 32 + lk8];
      f32x4 a1 = *(const f32x4*)&Pgw[l15 * 84 + ks * 32 + lk8 + 4];
      bf8 pa;
      pa[0] = (short)f2b(a0[0]); pa[1] = (short)f2b(a0[1]);
      pa[2] = (short)f2b(a0[2]); pa[3] = (short)f2b(a0[3]);
      pa[4] = (short)f2b(a1[0]); pa[5] = (short)f2b(a1[1]);
      pa[6] = (short)f2b(a1[2]); pa[7] = (short)f2b(a1[3]);
#pragma unroll
      for (int vf = 0; vf < 4; ++vf) {
        int vrow = vf * 16 + l15;
        int xo = (ks * 64 + lk8 * 2) ^ ((vrow & 7) << 4);
        bf8 vb_ = *(const bf8*)(Vbase + (vrow << 7) + xo);
        Oa[vf] = mfma16(pa, vb_, Oa[vf]);
      }
    }

    if (more) {
      asm volatile("s_waitcnt vmcnt(10)" ::: "memory");
      __builtin_amdgcn_s_barrier();
    }
  }

#pragma unroll
  for (int vf = 0; vf < 4; ++vf)
#pragma unroll
    for (int g = 0; g < 4; ++g) {
      int r = lg * 4 + g;
      int ig = i0 + w * 16 + r;
      float v = Oa[vf][g] / Lr[g];
      Ob[((long)(bh >> 4) * T_ + ig) * E_ + h * DH_ + vf * 16 + l15] = f2b(v);
    }
}

// ---------------------------------------------------------------- launch

extern "C" void kernel_launch(void* const* d_in, const int* in_sizes, int n_in,
                              void* d_out, int out_size, void* d_ws, size_t ws_size,
                              hipStream_t stream)
{
  const float* x    = (const float*)d_in[0];
  const float* mem  = (const float*)d_in[1];
  const float* cm0  = (const float*)d_in[2];
  const float* cm1  = (const float*)d_in[3];
  const float* ltm  = (const float*)d_in[4];
  const float* pos  = (const float*)d_in[5];
  const float* Wq   = (const float*)d_in[6];
  const float* Wkv  = (const float*)d_in[7];
  const float* Wout = (const float*)d_in[8];
  const float* bout = (const float*)d_in[9];

  char* ws = (char*)d_ws;
  u16* kvin  = (u16*)(ws + 0);          // dead after gemm_bt<1>
  u16* vtb   = (u16*)(ws + 0);          // reuses kvin region (written by k_vtrans after)
  u16* wq_b  = (u16*)(ws + 23076864);
  u16* wkv_b = (u16*)(ws + 25174016);
  u16* wout_b= (u16*)(ws + 29368320);
  u16* posb  = (u16*)(ws + 31465472);
  u16* qb    = (u16*)(ws + 38019072);
  u16* kb    = (u16*)(ws + 46407680);
  u16* vb    = (u16*)(ws + 70000640);
  u16* ob    = (u16*)(ws + 93593600);

  k_build_kvin<<<11268, 256, 0, stream>>>(x, mem, cm0, cm1, ltm, kvin);
  k_f2b4<<<1024, 256, 0, stream>>>(Wq, wq_b, 262144);
  k_f2b4<<<2048, 256, 0, stream>>>(Wkv, wkv_b, 524288);
  k_f2b4<<<1024, 256, 0, stream>>>(Wout, wout_b, 262144);
  k_posb<<<3200, 256, 0, stream>>>(pos, posb);
  k_zeropad<<<2016, 256, 0, stream>>>(kb, vb);

  gemm_bt<0><<<256, 256, 0, stream>>>(kvin, wq_b, qb, nullptr, nullptr, nullptr);
  gemm_bt<1><<<1424, 256, 0, stream>>>(kvin, wkv_b, kb, vb, nullptr, nullptr);
  k_vtrans<<<dim3(45, 64), 256, 0, stream>>>(vb, vtb);
  attn_kernel<<<dim3(8, 64), 512, 0, stream>>>(qb, kb, vtb, posb, ob);
  gemm_bt<2><<<256, 256, 0, stream>>>(ob, wout_b, nullptr, nullptr, (float*)d_out, bout);
}

// Round 8
// 528.496 us; speedup vs baseline: 1.3774x; 1.3774x over previous
//
#include <hip/hip_runtime.h>
#include <hip/hip_bf16.h>

#define B_    4
#define T_    1024
#define E_    1024
#define H_    16
#define DH_   64
#define KV_   2817
#define KVP_  2880
#define MEML_ 1793
#define POSP_ 3200
#define SC2_  0.18033688011112042f   /* (1/8) * log2(e) */

typedef __attribute__((ext_vector_type(4))) float f32x4;
typedef __attribute__((ext_vector_type(8))) short bf8;
typedef __attribute__((ext_vector_type(4))) unsigned short u16x4;
typedef __attribute__((ext_vector_type(8))) unsigned short u16x8;
typedef unsigned short u16;

static __device__ __forceinline__ u16 f2b(float f) {
  union { __hip_bfloat16 b; u16 s; } u;
  u.b = __float2bfloat16(f);
  return u.s;
}

static __device__ __forceinline__ void gl_lds16(const void* g, void* l) {
  __builtin_amdgcn_global_load_lds(
      (const __attribute__((address_space(1))) unsigned int*)g,
      (__attribute__((address_space(3))) unsigned int*)l, 16, 0, 0);
}

static __device__ __forceinline__ f32x4 mfma16(bf8 a, bf8 b, f32x4 c) {
  return __builtin_amdgcn_mfma_f32_16x16x32_bf16(a, b, c, 0, 0, 0);
}

// ---------------------------------------------------------------- prep kernels

__global__ void k_build_kvin(const float* __restrict__ x, const float* __restrict__ mem,
                             const float* __restrict__ cm0, const float* __restrict__ cm1,
                             const float* __restrict__ ltm, u16* __restrict__ kvin)
{
  int idx = blockIdx.x * 256 + threadIdx.x;          // one float4 per thread
  if (idx >= B_ * KV_ * 256) return;
  int e4 = idx & 255;
  int jt = idx >> 8;                                  // b*2817 + j
  int b = jt / KV_;
  int j = jt - b * KV_;
  const float* src;
  if (j < 1)          src = ltm + (long)b * E_;
  else if (j < 513)   src = cm0 + ((long)b * 512 + (j - 1)) * E_;
  else if (j < 769)   src = cm1 + ((long)b * 256 + (j - 513)) * E_;
  else if (j < 1793)  src = mem + ((long)b * 1024 + (j - 769)) * E_;
  else                src = x   + ((long)b * 1024 + (j - 1793)) * E_;
  float4 v = ((const float4*)src)[e4];
  u16x4 o; o[0] = f2b(v.x); o[1] = f2b(v.y); o[2] = f2b(v.z); o[3] = f2b(v.w);
  *(u16x4*)(kvin + (long)jt * E_ + e4 * 4) = o;
}

__global__ void k_f2b4(const float* __restrict__ s, u16* __restrict__ d, int n4)
{
  int i = blockIdx.x * 256 + threadIdx.x;
  if (i >= n4) return;
  float4 v = ((const float4*)s)[i];
  u16x4 o; o[0] = f2b(v.x); o[1] = f2b(v.y); o[2] = f2b(v.z); o[3] = f2b(v.w);
  *(u16x4*)(d + (long)i * 4) = o;
}

__global__ void k_posb(const float* __restrict__ pos, u16* __restrict__ pb)
{
  int idx = blockIdx.x * 256 + threadIdx.x;          // one float4 per thread
  if (idx >= H_ * POSP_ * 16) return;
  int e4 = idx & 15;
  int rest = idx >> 4;
  int m = rest % POSP_;
  int h = rest / POSP_;
  u16x4 o;
  if (m < KV_) {
    float4 v = ((const float4*)(pos + ((long)h * KV_ + m) * DH_))[e4];
    o[0] = f2b(v.x); o[1] = f2b(v.y); o[2] = f2b(v.z); o[3] = f2b(v.w);
  } else {
    o[0] = 0; o[1] = 0; o[2] = 0; o[3] = 0;
  }
  *(u16x4*)(pb + ((long)h * POSP_ + m) * DH_ + e4 * 4) = o;
}

// zero pad rows j in [2817, 2880) of K and V, both [b,h,j,d] layout
__global__ void k_zeropad(u16* __restrict__ kb, u16* __restrict__ vb)
{
  int idx = blockIdx.x * 256 + threadIdx.x;
  const int NK = 64 * 63 * 64;      // (b*h) * padrows * d
  if (idx < NK) {
    int bh = idx / (63 * 64);
    int r  = idx - bh * (63 * 64);
    int j  = 2817 + (r >> 6);
    int d  = r & 63;
    kb[((long)bh * KVP_ + j) * DH_ + d] = 0;
  } else if (idx < 2 * NK) {
    int i2 = idx - NK;
    int bh = i2 / (63 * 64);
    int r  = i2 - bh * (63 * 64);
    int j  = 2817 + (r >> 6);
    int d  = r & 63;
    vb[((long)bh * KVP_ + j) * DH_ + d] = 0;
  }
}

// transpose V: vb [bh][j 2880][d 64] -> vtb [bh][d 64][j 2880], 64x64 LDS tiles
__global__ __launch_bounds__(256)
void k_vtrans(const u16* __restrict__ vb, u16* __restrict__ vtb)
{
  __shared__ u16 tile[64][66];
  const int bh = blockIdx.y;
  const int j0 = blockIdx.x * 64;
  const u16* src = vb + ((long)bh * KVP_ + j0) * DH_;
  u16* dst = vtb + (long)bh * DH_ * KVP_ + j0;
  const int t = threadIdx.x;
#pragma unroll
  for (int c = 0; c < 2; ++c) {
    int lin = c * 256 + t;
    int r = lin >> 3, ch = (lin & 7) * 8;
    u16x8 v = *(const u16x8*)(src + (long)r * DH_ + ch);
    *(u16x4*)&tile[r][ch]     = *(const u16x4*)&v;
    *(u16x4*)&tile[r][ch + 4] = *(((const u16x4*)&v) + 1);
  }
  __syncthreads();
#pragma unroll
  for (int c = 0; c < 2; ++c) {
    int lin = c * 256 + t;
    int d = lin >> 3, jc = (lin & 7) * 8;
    u16x8 o;
#pragma unroll
    for (int e = 0; e < 8; ++e) o[e] = tile[jc + e][d];
    *(u16x8*)(dst + (long)d * KVP_ + jc) = o;
  }
}

// ---------------------------------------------------------------- GEMM (A[M,K] bf16 row-major, B[N,K] bf16 row-major -> C = A.B^T)
// Accumulators are 16 NAMED f32x4 registers (no arrays -> no scratch, rule #20).

template<int MODE>
__global__ __launch_bounds__(256)
void gemm_bt(const u16* __restrict__ A, const u16* __restrict__ Bw,
             u16* __restrict__ Out16, u16* __restrict__ Out16b,
             float* __restrict__ Outf, const float* __restrict__ bias)
{
  constexpr int Kd = 1024;
  constexpr int NT = (MODE == 1) ? 16 : 8;
  __shared__ u16 As[128 * 32];
  __shared__ u16 Bs[128 * 32];
  const int bid = blockIdx.x;
  const int mt = bid / NT, ntl = bid - mt * NT;
  const int m0 = mt * 128, n0 = ntl * 128;
  const int t = threadIdx.x;
  const int w = t >> 6, lane = t & 63;
  const int wr = w >> 1, wc = w & 1;
  const int l15 = lane & 15, lg = lane >> 4;
  const int xr = l15 & 3;                    // row&3 for fragment rows
  const int xo = (lg ^ xr) << 4;             // XOR-swizzled chunk byte offset

  f32x4 c00{}, c01{}, c02{}, c03{}, c10{}, c11{}, c12{}, c13{},
        c20{}, c21{}, c22{}, c23{}, c30{}, c31{}, c32{}, c33{};

  long growA[2]; int nrowB[2], xcA[2];
#pragma unroll
  for (int c = 0; c < 2; ++c) {
    int lin = c * 256 + t;
    int row = lin >> 2;
    xcA[c] = ((lin & 3) ^ (row & 3)) * 8;    // XOR-swizzled k-chunk (source side)
    int m = m0 + row;
    long grow;
    if (MODE == 0)      { int b = m >> 10; grow = (long)b * KV_ + MEML_ + (m & 1023); }
    else if (MODE == 1) { grow = (m > 11267) ? 11267 : m; }
    else                { grow = m; }
    growA[c] = grow;
    nrowB[c] = n0 + row;
  }

  const char* pa = (const char*)As + (wr * 64 + l15) * 64 + xo;
  const char* pb = (const char*)Bs + (wc * 64 + l15) * 64 + xo;

  for (int kt = 0; kt < Kd; kt += 32) {
#pragma unroll
    for (int c = 0; c < 2; ++c) {
      int lin = c * 256 + t;
      gl_lds16(A + growA[c] * Kd + kt + xcA[c], (char*)As + lin * 16);
      gl_lds16(Bw + (long)nrowB[c] * Kd + kt + xcA[c], (char*)Bs + lin * 16);
    }
    __syncthreads();
    bf8 a0 = *(const bf8*)(pa);
    bf8 a1 = *(const bf8*)(pa + 16 * 64);
    bf8 a2 = *(const bf8*)(pa + 32 * 64);
    bf8 a3 = *(const bf8*)(pa + 48 * 64);
    bf8 b0 = *(const bf8*)(pb);
    bf8 b1 = *(const bf8*)(pb + 16 * 64);
    bf8 b2 = *(const bf8*)(pb + 32 * 64);
    bf8 b3 = *(const bf8*)(pb + 48 * 64);
    c00 = mfma16(a0, b0, c00); c01 = mfma16(a0, b1, c01);
    c02 = mfma16(a0, b2, c02); c03 = mfma16(a0, b3, c03);
    c10 = mfma16(a1, b0, c10); c11 = mfma16(a1, b1, c11);
    c12 = mfma16(a1, b2, c12); c13 = mfma16(a1, b3, c13);
    c20 = mfma16(a2, b0, c20); c21 = mfma16(a2, b1, c21);
    c22 = mfma16(a2, b2, c22); c23 = mfma16(a2, b3, c23);
    c30 = mfma16(a3, b0, c30); c31 = mfma16(a3, b1, c31);
    c32 = mfma16(a3, b2, c32); c33 = mfma16(a3, b3, c33);
    __syncthreads();
  }

  auto epi = [&](int mi, int ni, f32x4 ac) {
    int mb = m0 + wr * 64 + mi * 16 + lg * 4;
    int n  = n0 + wc * 64 + ni * 16 + l15;
    if (MODE == 0) {
      int hh = n >> 6, d = n & 63;
#pragma unroll
      for (int g = 0; g < 4; ++g) {
        int m = mb + g; int b = m >> 10, tq = m & 1023;
        Out16[((long)(b * 16 + hh) * T_ + tq) * DH_ + d] = f2b(ac[g]);
      }
    } else if (MODE == 1) {
      if (n < 1024) {
        int hh = n >> 6, d = n & 63;
#pragma unroll
        for (int g = 0; g < 4; ++g) {
          int m = mb + g; if (m >= 11268) continue;
          int b = m / KV_, j = m - b * KV_;
          Out16[((long)(b * 16 + hh) * KVP_ + j) * DH_ + d] = f2b(ac[g]);
        }
      } else {
        int n2 = n - 1024, hh = n2 >> 6, d = n2 & 63;
#pragma unroll
        for (int g = 0; g < 4; ++g) {
          int m = mb + g; if (m >= 11268) continue;
          int b = m / KV_, j = m - b * KV_;
          Out16b[((long)(b * 16 + hh) * KVP_ + j) * DH_ + d] = f2b(ac[g]);
        }
      }
    } else {
      float bv = bias[n];
#pragma unroll
      for (int g = 0; g < 4; ++g) {
        int m = mb + g;
        Outf[(long)m * E_ + n] = ac[g] + bv;
      }
    }
  };

  epi(0, 0, c00); epi(0, 1, c01); epi(0, 2, c02); epi(0, 3, c03);
  epi(1, 0, c10); epi(1, 1, c11); epi(1, 2, c12); epi(1, 3, c13);
  epi(2, 0, c20); epi(2, 1, c21); epi(2, 2, c22); epi(2, 3, c23);
  epi(3, 0, c30); epi(3, 1, c31); epi(3, 2, c32); epi(3, 3, c33);
}

// ---------------------------------------------------------------- attention
// grid (8, 64): x = 128-row query tile (reversed order), y = b*16+h.
// 8 waves x 16 query rows, 512 threads. Double-buffered K/V LDS shared by
// all 8 waves, 2-phase pipeline with counted vmcnt, pos via direct global
// B-fragment loads software-pipelined one tile ahead.
// launch_bounds(512,2): VGPR cap 256 -> NO SPILLS (512,4 capped at 128 and
// spilled 800 MB/dispatch to scratch in round 7).

__global__ __launch_bounds__(512, 2)
void attn_kernel(const u16* __restrict__ Qb, const u16* __restrict__ Kb,
                 const u16* __restrict__ Vtb, const u16* __restrict__ Pb,
                 u16* __restrict__ Ob)
{
  __shared__ u16 Ks[2][64 * 64];    // [n][d], XOR-swizzled rows
  __shared__ u16 Vs[2][64 * 64];    // [d][n], XOR-swizzled rows
  __shared__ float Pg[8][16 * 84];  // per-wave scratch (pos gather, then P)

  const int i0 = (7 - blockIdx.x) * 128;   // reversed: longest blocks first
  const int bh = blockIdx.y;
  const int h  = bh & 15;
  const int t  = threadIdx.x;
  const int w  = t >> 6, lane = t & 63;
  const int l15 = lane & 15, lg = lane >> 4, lk8 = lg * 8;
  const int iwb = i0 + w * 16;

  const u16* Qp = Qb + ((long)bh * T_ + i0) * DH_;
  const u16* Kp = Kb + (long)bh * KVP_ * DH_;
  const u16* Vp = Vtb + (long)bh * DH_ * KVP_;
  const u16* Pp = Pb + (long)h * POSP_ * DH_;
  float* Pgw = &Pg[w][0];

  bf8 qf0 = *(const bf8*)(Qp + (w * 16 + l15) * DH_ + lk8);
  bf8 qf1 = *(const bf8*)(Qp + (w * 16 + l15) * DH_ + 32 + lk8);

  f32x4 Oa[4] = {};
  float Mr[4] = {-1e30f, -1e30f, -1e30f, -1e30f};
  float Lr[4] = {0.f, 0.f, 0.f, 0.f};

  const int ntiles = 31 + (i0 >> 6);

  // stage K,V tile tl into buffer bsel (2 gl_lds16 per thread, 512 threads)
  const int srow = t >> 3;
  const int ssc  = ((t & 7) ^ (srow & 7)) * 8;
  auto STAGE = [&](int tl, int bsel) {
    const int n0s = tl * 64;
    gl_lds16(Kp + (long)(n0s + srow) * DH_ + ssc, (char*)&Ks[bsel][0] + t * 16);
    gl_lds16(Vp + (long)srow * KVP_ + n0s + ssc, (char*)&Vs[bsel][0] + t * 16);
  };

  // pos band B-fragments for tile tl (10 named regs, 16B loads)
  bf8 p00, p01, p10, p11, p20, p21, p30, p31, p40, p41;
  auto POSLOAD = [&](int tl) {
    const u16* pp = Pp + (long)(tl * 64 - i0 + 1008 - 16 * w + l15) * DH_ + lk8;
    p00 = *(const bf8*)(pp);             p01 = *(const bf8*)(pp + 32);
    p10 = *(const bf8*)(pp + 16 * DH_);  p11 = *(const bf8*)(pp + 16 * DH_ + 32);
    p20 = *(const bf8*)(pp + 32 * DH_);  p21 = *(const bf8*)(pp + 32 * DH_ + 32);
    p30 = *(const bf8*)(pp + 48 * DH_);  p31 = *(const bf8*)(pp + 48 * DH_ + 32);
    p40 = *(const bf8*)(pp + 64 * DH_);  p41 = *(const bf8*)(pp + 64 * DH_ + 32);
  };

  // prologue: stage tile 0, preload pos tile 0, drain stages only
  STAGE(0, 0);
  __builtin_amdgcn_sched_barrier(0);
  POSLOAD(0);
  asm volatile("s_waitcnt vmcnt(10)" ::: "memory");
  __builtin_amdgcn_s_barrier();

  for (int tl = 0; tl < ntiles; ++tl) {
    const int bsel = tl & 1;
    const int n0 = tl * 64;
    const bool more = (tl + 1 < ntiles);
    if (more) STAGE(tl + 1, bsel ^ 1);
    __builtin_amdgcn_sched_barrier(0);

    const char* Kbase = (const char*)&Ks[bsel][0];
    const char* Vbase = (const char*)&Vs[bsel][0];

    // QK^T : 4 column fragments of 16 keys
    f32x4 sf[4];
#pragma unroll
    for (int cf = 0; cf < 4; ++cf) {
      int row = cf * 16 + l15;
      int x0 = (lk8 * 2) ^ ((row & 7) << 4);
      int x1 = (64 + lk8 * 2) ^ ((row & 7) << 4);
      f32x4 z = {0.f, 0.f, 0.f, 0.f};
      z = mfma16(qf0, *(const bf8*)(Kbase + (row << 7) + x0), z);
      z = mfma16(qf1, *(const bf8*)(Kbase + (row << 7) + x1), z);
      sf[cf] = z;
    }

    // pos band MFMAs from registers; scatter to per-wave scratch (stride 84)
    {
      f32x4 z0 = {0.f,0.f,0.f,0.f}, z1 = {0.f,0.f,0.f,0.f}, z2 = {0.f,0.f,0.f,0.f},
            z3 = {0.f,0.f,0.f,0.f}, z4 = {0.f,0.f,0.f,0.f};
      z0 = mfma16(qf0, p00, z0); z0 = mfma16(qf1, p01, z0);
      z1 = mfma16(qf0, p10, z1); z1 = mfma16(qf1, p11, z1);
      z2 = mfma16(qf0, p20, z2); z2 = mfma16(qf1, p21, z2);
      z3 = mfma16(qf0, p30, z3); z3 = mfma16(qf1, p31, z3);
      z4 = mfma16(qf0, p40, z4); z4 = mfma16(qf1, p41, z4);
#pragma unroll
      for (int g = 0; g < 4; ++g) {
        int rb = (lg * 4 + g) * 84 + l15;
        Pgw[rb]      = z0[g];
        Pgw[rb + 16] = z1[g];
        Pgw[rb + 32] = z2[g];
        Pgw[rb + 48] = z3[g];
        Pgw[rb + 64] = z4[g];
      }
    }
    if (more) POSLOAD(tl + 1);

    // diagonal gather + scale + mask
    float sv[4][4];
    const bool mm = (n0 + 63) > (MEML_ + iwb);
#pragma unroll
    for (int cf = 0; cf < 4; ++cf) {
      int c = cf * 16 + l15;
#pragma unroll
      for (int g = 0; g < 4; ++g) {
        int r = lg * 4 + g;
        float pv = Pgw[r * 84 + (c + 15 - r)];
        float s2 = (sf[cf][g] + pv) * SC2_;
        if (mm && (n0 + c) > (MEML_ + iwb + r)) s2 = -1e30f;
        sv[cf][g] = s2;
      }
    }
    // online softmax (exp2 domain), per query row
#pragma unroll
    for (int g = 0; g < 4; ++g) {
      float v = fmaxf(fmaxf(sv[0][g], sv[1][g]), fmaxf(sv[2][g], sv[3][g]));
      v = fmaxf(v, __shfl_xor(v, 1)); v = fmaxf(v, __shfl_xor(v, 2));
      v = fmaxf(v, __shfl_xor(v, 4)); v = fmaxf(v, __shfl_xor(v, 8));
      float Mn = fmaxf(Mr[g], v);
      float corr = exp2f(Mr[g] - Mn);
      Mr[g] = Mn;
      float p0 = exp2f(sv[0][g] - Mn), p1 = exp2f(sv[1][g] - Mn);
      float p2 = exp2f(sv[2][g] - Mn), p3 = exp2f(sv[3][g] - Mn);
      float ls = p0 + p1 + p2 + p3;
      ls += __shfl_xor(ls, 1); ls += __shfl_xor(ls, 2);
      ls += __shfl_xor(ls, 4); ls += __shfl_xor(ls, 8);
      Lr[g] = Lr[g] * corr + ls;
#pragma unroll
      for (int of = 0; of < 4; ++of) Oa[of][g] *= corr;
      int r = lg * 4 + g;
      Pgw[r * 84 + l15]      = p0;
      Pgw[r * 84 + 16 + l15] = p1;
      Pgw[r * 84 + 32 + l15] = p2;
      Pgw[r * 84 + 48 + l15] = p3;
    }
    // PV: read P back as A-fragments (f32 -> bf16), V from transposed LDS tile
#pragma unroll
    for (int ks = 0; ks < 2; ++ks) {
      f32x4 a0 = *(const f32x4*)&Pgw[l15 * 84 + ks * 32 + lk8];
      f32x4 a1 = *(const f32x4*)&Pgw[l15 * 84 + ks * 32 + lk8 + 4];
      bf8 pa;
      pa[0] = (short)f2b(a0[0]); pa[1] = (short)f2b(a0[1]);
      pa[2] = (short)f2b(a0[2]); pa[3] = (short)f2b(a0[3]);
      pa[4] = (short)f2b(a1[0]); pa[5] = (short)f2b(a1[1]);
      pa[6] = (short)f2b(a1[2]); pa[7] = (short)f2b(a1[3]);
#pragma unroll
      for (int vf = 0; vf < 4; ++vf) {
        int vrow = vf * 16 + l15;
        int xo = (ks * 64 + lk8 * 2) ^ ((vrow & 7) << 4);
        bf8 vb_ = *(const bf8*)(Vbase + (vrow << 7) + xo);
        Oa[vf] = mfma16(pa, vb_, Oa[vf]);
      }
    }

    if (more) {
      asm volatile("s_waitcnt vmcnt(10)" ::: "memory");
      __builtin_amdgcn_s_barrier();
    }
  }

#pragma unroll
  for (int vf = 0; vf < 4; ++vf)
#pragma unroll
    for (int g = 0; g < 4; ++g) {
      int r = lg * 4 + g;
      int ig = i0 + w * 16 + r;
      float v = Oa[vf][g] / Lr[g];
      Ob[((long)(bh >> 4) * T_ + ig) * E_ + h * DH_ + vf * 16 + l15] = f2b(v);
    }
}

// ---------------------------------------------------------------- launch

extern "C" void kernel_launch(void* const* d_in, const int* in_sizes, int n_in,
                              void* d_out, int out_size, void* d_ws, size_t ws_size,
                              hipStream_t stream)
{
  const float* x    = (const float*)d_in[0];
  const float* mem  = (const float*)d_in[1];
  const float* cm0  = (const float*)d_in[2];
  const float* cm1  = (const float*)d_in[3];
  const float* ltm  = (const float*)d_in[4];
  const float* pos  = (const float*)d_in[5];
  const float* Wq   = (const float*)d_in[6];
  const float* Wkv  = (const float*)d_in[7];
  const float* Wout = (const float*)d_in[8];
  const float* bout = (const float*)d_in[9];

  char* ws = (char*)d_ws;
  u16* kvin  = (u16*)(ws + 0);          // dead after gemm_bt<1>
  u16* vtb   = (u16*)(ws + 0);          // reuses kvin region (written by k_vtrans after)
  u16* wq_b  = (u16*)(ws + 23076864);
  u16* wkv_b = (u16*)(ws + 25174016);
  u16* wout_b= (u16*)(ws + 29368320);
  u16* posb  = (u16*)(ws + 31465472);
  u16* qb    = (u16*)(ws + 38019072);
  u16* kb    = (u16*)(ws + 46407680);
  u16* vb    = (u16*)(ws + 70000640);
  u16* ob    = (u16*)(ws + 93593600);

  k_build_kvin<<<11268, 256, 0, stream>>>(x, mem, cm0, cm1, ltm, kvin);
  k_f2b4<<<1024, 256, 0, stream>>>(Wq, wq_b, 262144);
  k_f2b4<<<2048, 256, 0, stream>>>(Wkv, wkv_b, 524288);
  k_f2b4<<<1024, 256, 0, stream>>>(Wout, wout_b, 262144);
  k_posb<<<3200, 256, 0, stream>>>(pos, posb);
  k_zeropad<<<2016, 256, 0, stream>>>(kb, vb);

  gemm_bt<0><<<256, 256, 0, stream>>>(kvin, wq_b, qb, nullptr, nullptr, nullptr);
  gemm_bt<1><<<1424, 256, 0, stream>>>(kvin, wkv_b, kb, vb, nullptr, nullptr);
  k_vtrans<<<dim3(45, 64), 256, 0, stream>>>(vb, vtb);
  attn_kernel<<<dim3(8, 64), 512, 0, stream>>>(qb, kb, vtb, posb, ob);
  gemm_bt<2><<<256, 256, 0, stream>>>(ob, wout_b, nullptr, nullptr, (float*)d_out, bout);
}